// Round 8
// baseline (3641.875 us; speedup 1.0000x reference)
//
#include <hip/hip_runtime.h>
#include <stdint.h>

typedef short short8 __attribute__((ext_vector_type(8)));
typedef float v4f __attribute__((ext_vector_type(4)));

#define EPI_BF16    0
#define EPI_GELU    1
#define EPI_XPOS    3
#define EPI_ATOM    5
#define EPI_ATOMOUT 6

__device__ __forceinline__ uint16_t f2bf(float f) {
  uint32_t u = __float_as_uint(f);
  u += 0x7fffu + ((u >> 16) & 1u);
  return (uint16_t)(u >> 16);
}
__device__ __forceinline__ float bf2f(uint16_t h) {
  return __uint_as_float(((uint32_t)h) << 16);
}
__device__ __forceinline__ float gelu_f(float v) {
  return 0.5f * v * (1.f + erff(v * 0.70710678118654752f));
}
__device__ __forceinline__ void gld16(const uint16_t* g, uint16_t* l) {
  __builtin_amdgcn_global_load_lds(
      (const __attribute__((address_space(1))) void*)g,
      (__attribute__((address_space(3))) void*)l, 16, 0, 0);
}

// ---------------------------------------------------------------------------
// Weight transpose+convert: src fp32 [K][N] -> dst bf16 [N][K], batched.
// ---------------------------------------------------------------------------
struct TDesc {
  const float* src;
  uint16_t* dst;
  int K, N, batch;
  long long sstride, dstride;
  int tilesK, tilesN;
  long long tileStart;
};
struct TTable {
  TDesc d[12];
  int nd;
  long long totalTiles;
};

__global__ __launch_bounds__(256) void transpose_convert_kernel(TTable tt) {
  __shared__ float tile[32][33];
  const int tid = threadIdx.x;
  for (long long t = blockIdx.x; t < tt.totalTiles; t += gridDim.x) {
    int di = 0;
    while (di + 1 < tt.nd && t >= tt.d[di + 1].tileStart) di++;
    const TDesc d = tt.d[di];
    long long loc = t - d.tileStart;
    int perB = d.tilesK * d.tilesN;
    int bi = (int)(loc / perB);
    int r = (int)(loc % perB);
    int tk = r / d.tilesN, tn = r % d.tilesN;
    const float* src = d.src + (long long)bi * d.sstride;
    uint16_t* dst = d.dst + (long long)bi * d.dstride;
    int k0 = tk * 32, n0 = tn * 32;
#pragma unroll
    for (int p = 0; p < 4; p++) {
      int i = (tid >> 5) + p * 8;
      int k = k0 + i, n = n0 + (tid & 31);
      float v = 0.f;
      if (k < d.K && n < d.N) v = src[(long long)k * d.N + n];
      tile[i][tid & 31] = v;
    }
    __syncthreads();
#pragma unroll
    for (int p = 0; p < 4; p++) {
      int i = (tid >> 5) + p * 8;
      int n = n0 + i, k = k0 + (tid & 31);
      if (n < d.N && k < d.K) dst[(long long)n * d.K + k] = f2bf(tile[tid & 31][i]);
    }
    __syncthreads();
  }
}

// ---------------------------------------------------------------------------
// conv_w fp32 [384][2048][9] -> bf16 [384][9*2048] with K order (tap, ic)
// ---------------------------------------------------------------------------
__global__ __launch_bounds__(256) void conv_w_transpose(const float* __restrict__ src,
                                                        uint16_t* __restrict__ dst) {
  __shared__ float lds[2304];
  const int n = blockIdx.y;
  const int c0 = blockIdx.x * 256;
  const float* s = src + (size_t)n * 18432 + (size_t)c0 * 9;
  for (int j = threadIdx.x; j < 2304; j += 256) lds[j] = s[j];
  __syncthreads();
#pragma unroll
  for (int tap = 0; tap < 9; tap++)
    dst[(size_t)n * 18432 + tap * 2048 + c0 + threadIdx.x] =
        f2bf(lds[threadIdx.x * 9 + tap]);
}

// ---------------------------------------------------------------------------
// img_feat fp32 [32][2048][16][16] -> padded NHWC bf16 [32][18][18][2048]
// ---------------------------------------------------------------------------
__global__ __launch_bounds__(256) void img_pad_kernel(const float* __restrict__ img,
                                                      uint16_t* __restrict__ imgp) {
  __shared__ float tile[64][65];
  const int tid = threadIdx.x;
  const int b = blockIdx.z, ict = blockIdx.y, xyt = blockIdx.x;
  const int ic0 = ict * 64, xy0 = xyt * 64;
  const float* src = img + ((size_t)b * 2048 + ic0) * 256 + xy0;
#pragma unroll
  for (int p = 0; p < 16; p++) {
    int i = (tid >> 6) + p * 4;
    int j = tid & 63;
    tile[i][j] = src[(size_t)i * 256 + j];
  }
  __syncthreads();
#pragma unroll
  for (int p = 0; p < 16; p++) {
    int j = (tid >> 6) + p * 4;
    int i = tid & 63;
    int xy = xy0 + j;
    int y = xy >> 4, x = xy & 15;
    imgp[(((size_t)b * 18 + y + 1) * 18 + (x + 1)) * 2048 + ic0 + i] = f2bf(tile[i][j]);
  }
}

// ---------------------------------------------------------------------------
// prep: concat qkv biases to fp32 [8][2304]; convert vm/fm patches to bf16
// ---------------------------------------------------------------------------
__global__ __launch_bounds__(256) void prep_kernel(const float* __restrict__ bq,
                                                   const float* __restrict__ bk,
                                                   const float* __restrict__ bv,
                                                   float* __restrict__ bqkv,
                                                   const float* __restrict__ vm,
                                                   const float* __restrict__ fm,
                                                   uint16_t* __restrict__ vmb,
                                                   uint16_t* __restrict__ fmb) {
  int idx = blockIdx.x * 256 + threadIdx.x;
  if (idx < 2097152) {
    vmb[idx] = f2bf(vm[idx]);
    fmb[idx] = f2bf(fm[idx]);
  }
  if (idx < 18432) {
    int l = idx / 2304, c = idx % 2304;
    float v = (c < 768) ? bq[l * 768 + c]
                        : ((c < 1536) ? bk[l * 768 + c - 768] : bv[l * 768 + c - 1536]);
    bqkv[idx] = v;
  }
}

// ---------------------------------------------------------------------------
// x[:, 0:384] = convb[n] + pos[t][n]
// ---------------------------------------------------------------------------
__global__ __launch_bounds__(256) void xinit_kernel(const float* __restrict__ convb,
                                                    const float* __restrict__ pos,
                                                    float* __restrict__ x) {
  int idx = blockIdx.x * 256 + threadIdx.x;
  if (idx >= 8192 * 384) return;
  int m = idx / 384, n = idx % 384;
  x[(size_t)m * 768 + n] = convb[n] + pos[(size_t)(m & 255) * 768 + n];
}

// ---------------------------------------------------------------------------
// LayerNorm over 768: one wave per row, pure shfl reduction.
// ---------------------------------------------------------------------------
template <int BF16IN>
__global__ __launch_bounds__(256) void ln_kernel(const void* __restrict__ inv,
                                                 const float* __restrict__ g,
                                                 const float* __restrict__ bta,
                                                 uint16_t* __restrict__ out) {
  const int wave = threadIdx.x >> 6, lane = threadIdx.x & 63;
  const int row = blockIdx.x * 4 + wave;
  const float* inf = (const float*)inv;
  const uint16_t* inb = (const uint16_t*)inv;
  const size_t base = (size_t)row * 768;
  float v[12];
#pragma unroll
  for (int i = 0; i < 12; i++) {
    int c = lane + i * 64;
    v[i] = BF16IN ? bf2f(inb[base + c]) : inf[base + c];
  }
  float s = 0.f, s2 = 0.f;
#pragma unroll
  for (int i = 0; i < 12; i++) {
    s += v[i];
    s2 += v[i] * v[i];
  }
#pragma unroll
  for (int d = 1; d < 64; d <<= 1) {
    s += __shfl_xor(s, d, 64);
    s2 += __shfl_xor(s2, d, 64);
  }
  float mean = s * (1.f / 768.f);
  float var = s2 * (1.f / 768.f) - mean * mean;
  float rs = rsqrtf(var + 1e-5f);
#pragma unroll
  for (int i = 0; i < 12; i++) {
    int c = lane + i * 64;
    out[base + c] = f2bf((v[i] - mean) * rs * g[c] + bta[c]);
  }
}

// ---------------------------------------------------------------------------
// Small-N GEMM (vm/fm embeds, N=192): 128x64 tile, serial K-loop.
// ---------------------------------------------------------------------------
template <int AMODE, int EPI>
__global__ __launch_bounds__(256, 4) void gemm_kernel(
    const uint16_t* __restrict__ A, const uint16_t* __restrict__ Bt,
    const float* __restrict__ bias, int N, int K,
    float* xout,
    const float* __restrict__ pos, int colOff,
    uint16_t* __restrict__ outb, float* __restrict__ outf, int ldc) {
  __shared__ uint16_t ldsA[8192];
  __shared__ uint16_t ldsB[4096];
  const int tid = threadIdx.x;
  const int lane = tid & 63, wave = tid >> 6;
  const int l15 = lane & 15, q8 = (lane >> 4) << 3;
  const int row0 = blockIdx.x * 128, col0 = blockIdx.y * 64;
  const int kPer = K / (int)gridDim.z;
  const int kbeg = kPer * (int)blockIdx.z;
  const int wm = wave & 1, wn = wave >> 1;

  const uint16_t* srcP[6];
  uint16_t* dstP[6];
#pragma unroll
  for (int c = 0; c < 6; c++) {
    int j = wave * 6 + c;
    if (j < 16) {
      int mt8 = j >> 1, ks = j & 1;
      int m = row0 + mt8 * 16 + l15;
      srcP[c] = A + (size_t)m * K + ks * 32 + q8;
      dstP[c] = &ldsA[j * 512];
    } else {
      int fb = j - 16;
      int nt = fb >> 1, ks = fb & 1;
      int n = col0 + nt * 16 + l15;
      srcP[c] = Bt + (size_t)n * K + ks * 32 + q8;
      dstP[c] = &ldsB[fb * 512];
    }
  }

  v4f acc[4][2];
#pragma unroll
  for (int i = 0; i < 4; i++)
#pragma unroll
    for (int j = 0; j < 2; j++) acc[i][j] = (v4f){0.f, 0.f, 0.f, 0.f};

  for (int k0 = kbeg; k0 < kbeg + kPer; k0 += 64) {
    __syncthreads();
#pragma unroll
    for (int c = 0; c < 6; c++) gld16(srcP[c] + (size_t)k0, dstP[c]);
    __syncthreads();
#pragma unroll
    for (int ks = 0; ks < 2; ks++) {
      short8 af[4], bfr[2];
#pragma unroll
      for (int mt = 0; mt < 4; mt++)
        af[mt] = *(const short8*)&ldsA[(((wm * 4 + mt) * 2) + ks) * 512 + lane * 8];
#pragma unroll
      for (int nt = 0; nt < 2; nt++)
        bfr[nt] = *(const short8*)&ldsB[(((wn * 2 + nt) * 2) + ks) * 512 + lane * 8];
#pragma unroll
      for (int mt = 0; mt < 4; mt++)
#pragma unroll
        for (int nt = 0; nt < 2; nt++)
          acc[mt][nt] =
              __builtin_amdgcn_mfma_f32_16x16x32_bf16(af[mt], bfr[nt], acc[mt][nt], 0, 0, 0);
    }
  }

#pragma unroll
  for (int mt = 0; mt < 4; mt++) {
    int mbase = row0 + wm * 64 + mt * 16 + ((lane >> 4) << 2);
#pragma unroll
    for (int nt = 0; nt < 2; nt++) {
      int n = col0 + wn * 32 + nt * 16 + l15;
      float bv;
      if (EPI == EPI_ATOM)
        bv = (bias != nullptr && blockIdx.z == 0) ? bias[n] : 0.f;
      else if (EPI == EPI_ATOMOUT)
        bv = (blockIdx.z == 0) ? bias[n] : 0.f;
      else
        bv = bias[n];
      v4f a = acc[mt][nt];
#pragma unroll
      for (int r = 0; r < 4; r++) {
        int m = mbase + r;
        float v = a[r] + bv;
        if (EPI == EPI_BF16) {
          outb[(size_t)m * ldc + n] = f2bf(v);
        } else if (EPI == EPI_GELU) {
          outb[(size_t)m * ldc + n] = f2bf(gelu_f(v));
        } else if (EPI == EPI_XPOS) {
          xout[(size_t)m * 768 + colOff + n] = v + pos[(size_t)(m & 255) * 768 + colOff + n];
        } else if (EPI == EPI_ATOM) {
          atomicAdd(&xout[(size_t)m * 768 + colOff + n], v);
        } else if (EPI == EPI_ATOMOUT) {
          atomicAdd(&outf[(size_t)m * ldc + n], v);
        }
      }
    }
  }
}

// ---------------------------------------------------------------------------
// Mid GEMM (dec/head): 128x128 tile, dbuf + counted vmcnt.
// ---------------------------------------------------------------------------
template <int EPI>
__global__ __launch_bounds__(256, 2) void gemm128_kernel(
    const uint16_t* __restrict__ A, const uint16_t* __restrict__ Bt,
    const float* __restrict__ bias, int N, int K,
    float* xout,
    uint16_t* __restrict__ outb, float* __restrict__ outf, int ldc) {
  __shared__ uint16_t lds[2][16384];
  const int tid = threadIdx.x;
  const int lane = tid & 63, wave = tid >> 6;
  const int l15 = lane & 15, q8 = (lane >> 4) << 3;
  const int row0 = blockIdx.x * 128, col0 = blockIdx.y * 128;
  const int kPer = K / (int)gridDim.z;
  const int kbeg = kPer * (int)blockIdx.z;
  const int nt = kPer >> 6;
  const int wm = wave & 1, wn = wave >> 1;

  const uint16_t* srcP[8];
  int off[8];
#pragma unroll
  for (int c = 0; c < 8; c++) {
    int j = wave * 8 + c;
    if (j < 16) {
      int mt8 = j >> 1, ks = j & 1;
      int m = row0 + mt8 * 16 + l15;
      srcP[c] = A + (size_t)m * K + kbeg + ks * 32 + q8;
      off[c] = j * 512;
    } else {
      int fb = j - 16;
      int nt16 = fb >> 1, ks = fb & 1;
      int n = col0 + nt16 * 16 + l15;
      srcP[c] = Bt + (size_t)n * K + kbeg + ks * 32 + q8;
      off[c] = 8192 + fb * 512;
    }
  }

  auto STAGE = [&](int t) {
    size_t ko = (size_t)(t * 64);
    uint16_t* lb = &lds[t & 1][0];
#pragma unroll
    for (int c = 0; c < 8; c++) gld16(srcP[c] + ko, lb + off[c]);
  };

  v4f acc[4][4];
#pragma unroll
  for (int i = 0; i < 4; i++)
#pragma unroll
    for (int j = 0; j < 4; j++) acc[i][j] = (v4f){0.f, 0.f, 0.f, 0.f};

  STAGE(0);
  if (nt > 1) STAGE(1);

  for (int t = 0; t < nt; t++) {
    if (t + 1 < nt)
      asm volatile("s_waitcnt vmcnt(8)" ::: "memory");
    else
      asm volatile("s_waitcnt vmcnt(0)" ::: "memory");
    __builtin_amdgcn_s_barrier();

    const uint16_t* lb = &lds[t & 1][0];
#pragma unroll
    for (int ks = 0; ks < 2; ks++) {
      short8 af[4], bfr[4];
#pragma unroll
      for (int mt = 0; mt < 4; mt++)
        af[mt] = *(const short8*)&lb[(((wm * 4 + mt) * 2) + ks) * 512 + lane * 8];
#pragma unroll
      for (int nt2 = 0; nt2 < 4; nt2++)
        bfr[nt2] = *(const short8*)&lb[8192 + (((wn * 4 + nt2) * 2) + ks) * 512 + lane * 8];
#pragma unroll
      for (int mt = 0; mt < 4; mt++)
#pragma unroll
        for (int nt2 = 0; nt2 < 4; nt2++)
          acc[mt][nt2] =
              __builtin_amdgcn_mfma_f32_16x16x32_bf16(af[mt], bfr[nt2], acc[mt][nt2], 0, 0, 0);
    }

    __builtin_amdgcn_s_barrier();
    if (t + 2 < nt) STAGE(t + 2);
  }

#pragma unroll
  for (int mt = 0; mt < 4; mt++) {
    int mbase = row0 + wm * 64 + mt * 16 + ((lane >> 4) << 2);
#pragma unroll
    for (int nt2 = 0; nt2 < 4; nt2++) {
      int n = col0 + wn * 64 + nt2 * 16 + l15;
      float bv;
      if (EPI == EPI_ATOMOUT)
        bv = (blockIdx.z == 0) ? bias[n] : 0.f;
      else
        bv = bias[n];
      v4f a = acc[mt][nt2];
#pragma unroll
      for (int r = 0; r < 4; r++) {
        int m = mbase + r;
        float v = a[r] + bv;
        if (EPI == EPI_BF16) {
          outb[(size_t)m * ldc + n] = f2bf(v);
        } else if (EPI == EPI_GELU) {
          outb[(size_t)m * ldc + n] = f2bf(gelu_f(v));
        } else if (EPI == EPI_ATOMOUT) {
          atomicAdd(&outf[(size_t)m * ldc + n], v);
        }
      }
    }
  }
}

// ---------------------------------------------------------------------------
// Main GEMM: 256x256 tile, 8-wave 4-phase schedule with read-ahead (verified
// r4/r5 sync skeleton; 512 threads = residency-feasible register budget).
// ---------------------------------------------------------------------------
template <int AMODE, int EPI>
__global__ __launch_bounds__(512, 2) void gemm256_kernel(
    const uint16_t* __restrict__ A, const uint16_t* __restrict__ Bt,
    const float* __restrict__ bias, int N, int K,
    float* xout, uint16_t* __restrict__ outb, float* __restrict__ outf, int ldc) {
  extern __shared__ uint16_t lds[];  // [2][32768]: per buf A 16384 | B 16384
  const int tid = threadIdx.x;
  const int lane = tid & 63, wave = tid >> 6;
  const int l15 = lane & 15, q8 = (lane >> 4) << 3;
  const int row0 = blockIdx.x * 256, col0 = blockIdx.y * 256;
  const int kPer = K / (int)gridDim.z;
  const int kbeg = kPer * (int)blockIdx.z;
  const int nt = kPer >> 6;
  const int wm = wave >> 2, wn = wave & 3;

  const uint16_t* src[4][2];
  int ldsoff[4][2];
#pragma unroll
  for (int c = 0; c < 2; c++) {
    int sub = wave * 2 + c;  // [0,16)
    int hf = sub >> 1, ks = sub & 1;
    int kin = ks * 32 + q8;
    int m0 = row0 + hf * 16 + l15;
    int m1 = m0 + 128;
    if (AMODE == 0) {
      src[0][c] = A + (size_t)m0 * K + kin;
      src[3][c] = A + (size_t)m1 * K + kin;
    } else {
      int b0_ = m0 >> 8, y0_ = (m0 >> 4) & 15, x0_ = m0 & 15;
      src[0][c] = A + ((size_t)((b0_ * 18 + y0_) * 18 + x0_)) * 2048 + kin;
      int b1_ = m1 >> 8, y1_ = (m1 >> 4) & 15, x1_ = m1 & 15;
      src[3][c] = A + ((size_t)((b1_ * 18 + y1_) * 18 + x1_)) * 2048 + kin;
    }
    src[1][c] = Bt + (size_t)(col0 + hf * 16 + l15) * K + kin;
    src[2][c] = Bt + (size_t)(col0 + 128 + hf * 16 + l15) * K + kin;
    ldsoff[0][c] = sub * 512;
    ldsoff[3][c] = (16 + sub) * 512;
    ldsoff[1][c] = 16384 + sub * 512;
    ldsoff[2][c] = 16384 + (16 + sub) * 512;
  }

#define STAGEH(TT, Q)                                                          \
  do {                                                                         \
    int t_ = (TT);                                                             \
    if (t_ < nt) {                                                             \
      int k0_ = kbeg + t_ * 64;                                                \
      size_t o_;                                                               \
      if (AMODE == 1 && ((Q) == 0 || (Q) == 3)) {                              \
        int kq_ = k0_ >> 11;                                                   \
        int ky_ = (kq_ >= 6) ? 2 : ((kq_ >= 3) ? 1 : 0);                       \
        int kx_ = kq_ - ky_ * 3;                                               \
        o_ = (size_t)((ky_ * 18 + kx_) * 2048) + (size_t)(k0_ & 2047);         \
      } else {                                                                 \
        o_ = (size_t)k0_;                                                      \
      }                                                                        \
      uint16_t* lb_ = &lds[(t_ & 1) * 32768];                                  \
      gld16(src[Q][0] + o_, lb_ + ldsoff[Q][0]);                               \
      gld16(src[Q][1] + o_, lb_ + ldsoff[Q][1]);                               \
    }                                                                          \
  } while (0)

  v4f acc[8][4];
#pragma unroll
  for (int i = 0; i < 8; i++)
#pragma unroll
    for (int j = 0; j < 4; j++) acc[i][j] = (v4f){0.f, 0.f, 0.f, 0.f};

  STAGEH(0, 0); STAGEH(0, 1); STAGEH(0, 2); STAGEH(0, 3);
  STAGEH(1, 1); STAGEH(1, 0);
  asm volatile("s_waitcnt vmcnt(4)" ::: "memory");
  __builtin_amdgcn_s_barrier();

  short8 a_[4][2], aN[4][2], b0_[2][2], b1_[2][2];

#pragma unroll
  for (int mt = 0; mt < 4; mt++)
#pragma unroll
    for (int ks = 0; ks < 2; ks++)
      aN[mt][ks] = *(const short8*)&lds[((wm * 8 + mt) * 2 + ks) * 512 + lane * 8];

  for (int t = 0; t < nt; t++) {
    const int bufo = (t & 1) * 32768;

#pragma unroll
    for (int nl = 0; nl < 2; nl++)
#pragma unroll
      for (int ks = 0; ks < 2; ks++)
        b0_[nl][ks] =
            *(const short8*)&lds[bufo + 16384 + ((wn * 4 + nl) * 2 + ks) * 512 + lane * 8];
#pragma unroll
    for (int nl = 0; nl < 2; nl++)
#pragma unroll
      for (int ks = 0; ks < 2; ks++)
        b1_[nl][ks] =
            *(const short8*)&lds[bufo + 16384 + ((wn * 4 + 2 + nl) * 2 + ks) * 512 + lane * 8];
    STAGEH(t + 1, 2);
    __builtin_amdgcn_s_barrier();
    __builtin_amdgcn_s_setprio(1);
#pragma unroll
    for (int mt = 0; mt < 4; mt++)
#pragma unroll
      for (int nl = 0; nl < 2; nl++)
#pragma unroll
        for (int ks = 0; ks < 2; ks++)
          acc[mt][nl] =
              __builtin_amdgcn_mfma_f32_16x16x32_bf16(aN[mt][ks], b0_[nl][ks], acc[mt][nl], 0, 0, 0);
    __builtin_amdgcn_s_setprio(0);
    __builtin_amdgcn_s_barrier();

#pragma unroll
    for (int mt = 0; mt < 4; mt++)
#pragma unroll
      for (int ks = 0; ks < 2; ks++)
        a_[mt][ks] =
            *(const short8*)&lds[bufo + ((wm * 8 + 4 + mt) * 2 + ks) * 512 + lane * 8];
    STAGEH(t + 1, 3);
    __builtin_amdgcn_s_barrier();
    __builtin_amdgcn_s_setprio(1);
#pragma unroll
    for (int mt = 0; mt < 4; mt++)
#pragma unroll
      for (int nl = 0; nl < 2; nl++)
#pragma unroll
        for (int ks = 0; ks < 2; ks++)
          acc[mt][2 + nl] =
              __builtin_amdgcn_mfma_f32_16x16x32_bf16(aN[mt][ks], b1_[nl][ks], acc[mt][2 + nl], 0, 0, 0);
    __builtin_amdgcn_s_setprio(0);
    __builtin_amdgcn_s_barrier();

    STAGEH(t + 2, 1);
    __builtin_amdgcn_s_barrier();
    __builtin_amdgcn_s_setprio(1);
#pragma unroll
    for (int mt = 0; mt < 4; mt++)
#pragma unroll
      for (int nl = 0; nl < 2; nl++)
#pragma unroll
        for (int ks = 0; ks < 2; ks++)
          acc[4 + mt][2 + nl] =
              __builtin_amdgcn_mfma_f32_16x16x32_bf16(a_[mt][ks], b1_[nl][ks], acc[4 + mt][2 + nl], 0, 0, 0);
    __builtin_amdgcn_s_setprio(0);
    __builtin_amdgcn_s_barrier();

    STAGEH(t + 2, 0);
    if (t < nt - 1) {
      if (t == nt - 2)
        asm volatile("s_waitcnt vmcnt(0)" ::: "memory");
      else
        asm volatile("s_waitcnt vmcnt(4)" ::: "memory");
    }
    __builtin_amdgcn_s_barrier();
    if (t + 1 < nt) {
      const int bufn = ((t + 1) & 1) * 32768;
#pragma unroll
      for (int mt = 0; mt < 4; mt++)
#pragma unroll
        for (int ks = 0; ks < 2; ks++)
          aN[mt][ks] =
              *(const short8*)&lds[bufn + ((wm * 8 + mt) * 2 + ks) * 512 + lane * 8];
    }
    __builtin_amdgcn_s_setprio(1);
#pragma unroll
    for (int mt = 0; mt < 4; mt++)
#pragma unroll
      for (int nl = 0; nl < 2; nl++)
#pragma unroll
        for (int ks = 0; ks < 2; ks++)
          acc[4 + mt][nl] =
              __builtin_amdgcn_mfma_f32_16x16x32_bf16(a_[mt][ks], b0_[nl][ks], acc[4 + mt][nl], 0, 0, 0);
    __builtin_amdgcn_s_setprio(0);
    __builtin_amdgcn_s_barrier();
  }
#undef STAGEH

#pragma unroll
  for (int mt = 0; mt < 8; mt++) {
    int mbase = row0 + wm * 128 + mt * 16 + ((lane >> 4) << 2);
#pragma unroll
    for (int nl = 0; nl < 4; nl++) {
      int n = col0 + wn * 64 + nl * 16 + l15;
      float bv;
      if (EPI == EPI_ATOM)
        bv = (bias != nullptr && blockIdx.z == 0) ? bias[n] : 0.f;
      else
        bv = bias[n];
      v4f a = acc[mt][nl];
#pragma unroll
      for (int r = 0; r < 4; r++) {
        int m = mbase + r;
        float v = a[r] + bv;
        if (EPI == EPI_BF16) {
          outb[(size_t)m * ldc + n] = f2bf(v);
        } else if (EPI == EPI_GELU) {
          outb[(size_t)m * ldc + n] = f2bf(gelu_f(v));
        } else if (EPI == EPI_ATOM) {
          atomicAdd(&xout[(size_t)m * 768 + n], v);
        }
      }
    }
  }
}

// ---------------------------------------------------------------------------
// Fused attention, restructured: ONE BLOCK PER (head, batch), 512 threads
// (8 waves), qc loop inside. K/V staged ONCE per (h,b) — the old (qc,h,b)
// grid staged the same K/V 4x, and the 4 qc-blocks landed on different XCDs
// (qc fastest-varying) so the re-reads missed L2 (~98 MB/dispatch of K/V
// traffic vs 24.6 MB minimal). P no longer aliases K -> after the single
// stage barrier, Kl/Vt are read-only and each wave owns a private P strip:
// NO barriers in the main loop. Per-wave P write->read is same-wave
// cross-lane -> s_waitcnt lgkmcnt(0) suffices.
// LDS: Kl 36.9K + Vt 33.8K + Pl 67.6K = 138.2 KB -> 1 block/CU, 8 waves.
// Grid (12,32)=384 blocks = 1.5 rounds (vs 3 rounds of 1536 blocks before).
// Per-q-row arithmetic identical to r7 -> absmax unchanged.
// ---------------------------------------------------------------------------
__global__ __launch_bounds__(512) void attn_kernel(const uint16_t* __restrict__ qkv,
                                                   uint16_t* __restrict__ y) {
  __shared__ uint16_t Kl[256 * 72];     // 36,864 B
  __shared__ uint16_t Vt[64 * 264];     // 33,792 B, col-swizzled
  __shared__ uint16_t Pl[8][16 * 264];  // 67,584 B, per-wave strip
  const int tid = threadIdx.x, lane = tid & 63, wave = tid >> 6;
  const int h = blockIdx.x, b = blockIdx.y;
  const uint16_t* base = qkv + (size_t)b * 256 * 2304;
  const uint16_t* kb = base + 768 + h * 64;
  const uint16_t* vb = base + 1536 + h * 64;

#pragma unroll
  for (int i = 0; i < 4; i++) {
    int c = i * 512 + tid;
    int t = c >> 3, dh = (c & 7) * 8;
    uint4 d = *(const uint4*)(kb + (size_t)t * 2304 + dh);
    *(uint4*)&Kl[t * 72 + dh] = d;
  }
#pragma unroll
  for (int i = 0; i < 4; i++) {
    int c = i * 512 + tid;
    int t = c >> 3, dh = (c & 7) * 8;
    uint4 d = *(const uint4*)(vb + (size_t)t * 2304 + dh);
    const uint16_t* e = (const uint16_t*)&d;
    int tc = t ^ (((dh >> 3) & 7) << 3);  // col swizzle (row>>3 == dh>>3)
#pragma unroll
    for (int j = 0; j < 8; j++) Vt[(dh + j) * 264 + tc] = e[j];
  }
  __syncthreads();  // Kl/Vt read-only from here; waves fully independent

  const uint16_t* qb = base + h * 64;
  const int l15 = lane & 15, q4 = (lane >> 4) << 3;
  const int rbase = (lane >> 4) << 2;

#pragma unroll 1
  for (int sub = 0; sub < 2; sub++) {
    const int t0 = wave * 32 + sub * 16;
    short8 aq0 = *(const short8*)(qb + (size_t)(t0 + l15) * 2304 + q4);
    short8 aq1 = *(const short8*)(qb + (size_t)(t0 + l15) * 2304 + 32 + q4);

    v4f s[16];
#pragma unroll
    for (int jt = 0; jt < 16; jt++) {
      short8 b0 = *(const short8*)&Kl[(jt * 16 + l15) * 72 + q4];
      short8 b1 = *(const short8*)&Kl[(jt * 16 + l15) * 72 + 32 + q4];
      v4f z = (v4f){0.f, 0.f, 0.f, 0.f};
      z = __builtin_amdgcn_mfma_f32_16x16x32_bf16(aq0, b0, z, 0, 0, 0);
      s[jt] = __builtin_amdgcn_mfma_f32_16x16x32_bf16(aq1, b1, z, 0, 0, 0);
    }

    float mx[4], sm[4];
#pragma unroll
    for (int r = 0; r < 4; r++) mx[r] = -1e30f;
#pragma unroll
    for (int jt = 0; jt < 16; jt++)
#pragma unroll
      for (int r = 0; r < 4; r++) {
        float v = s[jt][r] * 0.125f;
        s[jt][r] = v;
        mx[r] = fmaxf(mx[r], v);
      }
#pragma unroll
    for (int r = 0; r < 4; r++) {
#pragma unroll
      for (int d = 1; d < 16; d <<= 1) mx[r] = fmaxf(mx[r], __shfl_xor(mx[r], d, 64));
      sm[r] = 0.f;
    }
#pragma unroll
    for (int jt = 0; jt < 16; jt++)
#pragma unroll
      for (int r = 0; r < 4; r++) {
        float e = __expf(s[jt][r] - mx[r]);
        s[jt][r] = e;
        sm[r] += e;
      }
#pragma unroll
    for (int r = 0; r < 4; r++) {
#pragma unroll
      for (int d = 1; d < 16; d <<= 1) sm[r] += __shfl_xor(sm[r], d, 64);
      sm[r] = 1.f / sm[r];
    }

#pragma unroll
    for (int jt = 0; jt < 16; jt++)
#pragma unroll
      for (int r = 0; r < 4; r++)
        Pl[wave][(rbase + r) * 264 + jt * 16 + l15] = f2bf(s[jt][r] * sm[r]);
    // own-strip write -> same-wave cross-lane read: drain LDS queue
    asm volatile("s_waitcnt lgkmcnt(0)" ::: "memory");

    v4f o[4];
#pragma unroll
    for (int nt = 0; nt < 4; nt++) o[nt] = (v4f){0.f, 0.f, 0.f, 0.f};
#pragma unroll
    for (int ks = 0; ks < 8; ks++) {
      short8 ap = *(const short8*)&Pl[wave][l15 * 264 + ks * 32 + q4];
#pragma unroll
      for (int nt = 0; nt < 4; nt++) {
        int row = nt * 16 + l15;
        int col = (ks * 32 + q4) ^ (((row >> 3) & 7) << 3);
        short8 bv8 = *(const short8*)&Vt[row * 264 + col];
        o[nt] = __builtin_amdgcn_mfma_f32_16x16x32_bf16(ap, bv8, o[nt], 0, 0, 0);
      }
    }
#pragma unroll
    for (int nt = 0; nt < 4; nt++)
#pragma unroll
      for (int r = 0; r < 4; r++)
        y[(size_t)(b * 256 + t0 + rbase + r) * 768 + h * 64 + nt * 16 + l15] =
            f2bf(o[nt][r]);
  }
}

// ---------------------------------------------------------------------------
// host
// ---------------------------------------------------------------------------
extern "C" void kernel_launch(void* const* d_in, const int* in_sizes, int n_in,
                              void* d_out, int out_size, void* d_ws, size_t ws_size,
                              hipStream_t stream) {
  const float* img   = (const float*)d_in[0];
  const float* vmp   = (const float*)d_in[1];
  const float* fmp   = (const float*)d_in[2];
  const float* convw = (const float*)d_in[3];
  const float* convb = (const float*)d_in[4];
  const float* vmw   = (const float*)d_in[5];
  const float* vmb_  = (const float*)d_in[6];
  const float* fmw   = (const float*)d_in[7];
  const float* fmb_  = (const float*)d_in[8];
  const float* pos   = (const float*)d_in[9];
  const float* ln1g  = (const float*)d_in[10];
  const float* ln1b  = (const float*)d_in[11];
  const float* Wq    = (const float*)d_in[12];
  const float* bq    = (const float*)d_in[13];
  const float* Wk    = (const float*)d_in[14];
  const float* bk    = (const float*)d_in[15];
  const float* Wv    = (const float*)d_in[16];
  const float* bv    = (const float*)d_in[17];
  const float* Wo    = (const float*)d_in[18];
  const float* bo    = (const float*)d_in[19];
  const float* ln2g  = (const float*)d_in[20];
  const float* ln2b  = (const float*)d_in[21];
  const float* W1    = (const float*)d_in[22];
  const float* b1    = (const float*)d_in[23];
  const float* W2    = (const float*)d_in[24];
  const float* b2    = (const float*)d_in[25];
  const float* dln1g = (const float*)d_in[26];
  const float* dln1b = (const float*)d_in[27];
  const float* decw  = (const float*)d_in[28];
  const float* decb  = (const float*)d_in[29];
  const float* dln2g = (const float*)d_in[30];
  const float* dln2b = (const float*)d_in[31];
  const float* headw = (const float*)d_in[32];
  const float* headb = (const float*)d_in[33];
  float* out = (float*)d_out;

  char* wsb = (char*)d_ws;
  size_t off = 0;
  auto alloc = [&](size_t nbytes) -> void* {
    off = (off + 255) & ~(size_t)255;
    void* p = wsb + off;
    off += nbytes;
    return p;
  };
  uint16_t* WtQKV  = (uint16_t*)alloc(8ull * 2304 * 768 * 2);
  uint16_t* WtO    = (uint16_t*)alloc(8ull * 768 * 768 * 2);
  uint16_t* Wt1    = (uint16_t*)alloc(8ull * 3072 * 768 * 2);
  uint16_t* Wt2    = (uint16_t*)alloc(8ull * 768 * 3072 * 2);
  uint16_t* WtConv = (uint16_t*)alloc(512ull * 9 * 2048 * 2);  // padded to 512 rows
  uint16_t* WtVm   = (uint16_t*)alloc(192ull * 256 * 2);
  uint16_t* WtFm   = (uint16_t*)alloc(192ull * 256 * 2);
  uint16_t* WtDec  = (uint16_t*)alloc(768ull * 768 * 2);
  uint16_t* WtHead = (uint16_t*)alloc(256ull * 768 * 2);
  uint16_t* imgp   = (uint16_t*)alloc(32ull * 18 * 18 * 2048 * 2);
  uint16_t* vmb    = (uint16_t*)alloc(8192ull * 256 * 2);
  uint16_t* fmb    = (uint16_t*)alloc(8192ull * 256 * 2);
  float*    bqkv   = (float*)alloc(8ull * 2304 * 4);
  float*    x      = (float*)alloc(8192ull * 768 * 4);
  uint16_t* hbuf   = (uint16_t*)alloc(8192ull * 768 * 2);
  uint16_t* qkvb   = (uint16_t*)alloc(8192ull * 2304 * 2);
  uint16_t* ybuf   = (uint16_t*)alloc(8192ull * 768 * 2);
  uint16_t* ubuf   = (uint16_t*)alloc(8192ull * 3072 * 2);
  uint16_t* u2buf  = (uint16_t*)alloc(8192ull * 768 * 2);
  if (off > ws_size) return;

  hipMemsetAsync(imgp, 0, 32ull * 18 * 18 * 2048 * 2, stream);
  hipMemsetAsync(WtConv, 0, 512ull * 9 * 2048 * 2, stream);
  hipMemsetAsync(out, 0, (size_t)out_size * 4, stream);

  hipFuncSetAttribute((const void*)gemm256_kernel<1, EPI_ATOM>,
                      hipFuncAttributeMaxDynamicSharedMemorySize, 131072);
  hipFuncSetAttribute((const void*)gemm256_kernel<0, EPI_ATOM>,
                      hipFuncAttributeMaxDynamicSharedMemorySize, 131072);
  hipFuncSetAttribute((const void*)gemm256_kernel<0, EPI_BF16>,
                      hipFuncAttributeMaxDynamicSharedMemorySize, 131072);
  hipFuncSetAttribute((const void*)gemm256_kernel<0, EPI_GELU>,
                      hipFuncAttributeMaxDynamicSharedMemorySize, 131072);

  TTable tt;
  int nd = 0;
  long long tiles = 0;
  auto addT = [&](const float* src, uint16_t* dst, int K, int N, int batch,
                  long long sstr, long long dstr) {
    TDesc& d = tt.d[nd];
    d.src = src; d.dst = dst; d.K = K; d.N = N; d.batch = batch;
    d.sstride = sstr; d.dstride = dstr;
    d.tilesK = (K + 31) / 32; d.tilesN = (N + 31) / 32;
    d.tileStart = tiles;
    tiles += (long long)d.tilesK * d.tilesN * batch;
    nd++;
  };
  addT(Wq, WtQKV,           768, 768, 8, 589824, 1769472);
  addT(Wk, WtQKV + 589824,  768, 768, 8, 589824, 1769472);
  addT(Wv, WtQKV + 1179648, 768, 768, 8, 589824, 1769472);
  addT(Wo, WtO,             768, 768, 8, 589824, 589824);
  addT(W1, Wt1,             768, 3072, 8, 2359296, 2359296);
  addT(W2, Wt2,             3072, 768, 8, 2359296, 2359296);
  addT(vmw, WtVm,           256, 192, 1, 0, 0);
  addT(fmw, WtFm,           256, 192, 1, 0, 0);
  addT(decw, WtDec,         768, 768, 1, 0, 0);
  addT(headw, WtHead,       768, 256, 1, 0, 0);
  tt.nd = nd;
  tt.totalTiles = tiles;

  transpose_convert_kernel<<<(int)tiles, 256, 0, stream>>>(tt);
  conv_w_transpose<<<dim3(8, 384), 256, 0, stream>>>(convw, WtConv);
  img_pad_kernel<<<dim3(4, 32, 32), 256, 0, stream>>>(img, imgp);
  prep_kernel<<<8192, 256, 0, stream>>>(bq, bk, bv, bqkv, vmp, fmp, vmb, fmb);
  xinit_kernel<<<12288, 256, 0, stream>>>(convb, pos, x);

  // conv token embed: N padded 384->512, grid exactly 256 blocks.
  gemm256_kernel<1, EPI_ATOM><<<dim3(32, 2, 4), 512, 131072, stream>>>(
      imgp, WtConv, nullptr, 512, 18432, x, nullptr, nullptr, 0);
  gemm_kernel<0, EPI_XPOS><<<dim3(64, 3), 256, 0, stream>>>(
      vmb, WtVm, vmb_, 192, 256, x, pos, 384, nullptr, nullptr, 0);
  gemm_kernel<0, EPI_XPOS><<<dim3(64, 3), 256, 0, stream>>>(
      fmb, WtFm, fmb_, 192, 256, x, pos, 576, nullptr, nullptr, 0);

  for (int l = 0; l < 8; l++) {
    ln_kernel<0><<<2048, 256, 0, stream>>>(x, ln1g + l * 768, ln1b + l * 768, hbuf);
    gemm256_kernel<0, EPI_BF16><<<dim3(32, 9), 512, 131072, stream>>>(
        hbuf, WtQKV + (size_t)l * 1769472, bqkv + l * 2304, 2304, 768,
        nullptr, qkvb, nullptr, 2304);
    attn_kernel<<<dim3(12, 32), 512, 0, stream>>>(qkvb, ybuf);
    gemm256_kernel<0, EPI_ATOM><<<dim3(32, 3, 2), 512, 131072, stream>>>(
        ybuf, WtO + (size_t)l * 589824, bo + l * 768, 768, 768,
        x, nullptr, nullptr, 0);
    ln_kernel<0><<<2048, 256, 0, stream>>>(x, ln2g + l * 768, ln2b + l * 768, hbuf);
    gemm256_kernel<0, EPI_GELU><<<dim3(32, 12), 512, 131072, stream>>>(
        hbuf, Wt1 + (size_t)l * 2359296, b1 + l * 3072, 3072, 768,
        nullptr, ubuf, nullptr, 3072);
    gemm256_kernel<0, EPI_ATOM><<<dim3(32, 3, 2), 512, 131072, stream>>>(
        ubuf, Wt2 + (size_t)l * 2359296, b2 + l * 768, 768, 3072,
        x, nullptr, nullptr, 0);
  }

  ln_kernel<0><<<2048, 256, 0, stream>>>(x, dln1g, dln1b, hbuf);
  gemm128_kernel<EPI_GELU><<<dim3(64, 6), 256, 0, stream>>>(
      hbuf, WtDec, decb, 768, 768, nullptr, u2buf, nullptr, 768);
  ln_kernel<1><<<2048, 256, 0, stream>>>(u2buf, dln2g, dln2b, hbuf);
  gemm128_kernel<EPI_ATOMOUT><<<dim3(64, 2, 2), 256, 0, stream>>>(
      hbuf, WtHead, headb, 256, 768, nullptr, nullptr, out, 256);
}

// Round 9
// 3277.600 us; speedup vs baseline: 1.1111x; 1.1111x over previous
//
#include <hip/hip_runtime.h>
#include <stdint.h>

typedef short short8 __attribute__((ext_vector_type(8)));
typedef float v4f __attribute__((ext_vector_type(4)));

#define EPI_BF16    0
#define EPI_GELU    1
#define EPI_XPOS    3
#define EPI_ATOM    5
#define EPI_ATOMOUT 6

__device__ __forceinline__ uint16_t f2bf(float f) {
  uint32_t u = __float_as_uint(f);
  u += 0x7fffu + ((u >> 16) & 1u);
  return (uint16_t)(u >> 16);
}
__device__ __forceinline__ float bf2f(uint16_t h) {
  return __uint_as_float(((uint32_t)h) << 16);
}
__device__ __forceinline__ float gelu_f(float v) {
  return 0.5f * v * (1.f + erff(v * 0.70710678118654752f));
}
__device__ __forceinline__ void gld16(const uint16_t* g, uint16_t* l) {
  __builtin_amdgcn_global_load_lds(
      (const __attribute__((address_space(1))) void*)g,
      (__attribute__((address_space(3))) void*)l, 16, 0, 0);
}

// ---------------------------------------------------------------------------
// Weight transpose+convert: src fp32 [K][N] -> dst bf16 [N][K], batched.
// ---------------------------------------------------------------------------
struct TDesc {
  const float* src;
  uint16_t* dst;
  int K, N, batch;
  long long sstride, dstride;
  int tilesK, tilesN;
  long long tileStart;
};
struct TTable {
  TDesc d[12];
  int nd;
  long long totalTiles;
};

__global__ __launch_bounds__(256) void transpose_convert_kernel(TTable tt) {
  __shared__ float tile[32][33];
  const int tid = threadIdx.x;
  for (long long t = blockIdx.x; t < tt.totalTiles; t += gridDim.x) {
    int di = 0;
    while (di + 1 < tt.nd && t >= tt.d[di + 1].tileStart) di++;
    const TDesc d = tt.d[di];
    long long loc = t - d.tileStart;
    int perB = d.tilesK * d.tilesN;
    int bi = (int)(loc / perB);
    int r = (int)(loc % perB);
    int tk = r / d.tilesN, tn = r % d.tilesN;
    const float* src = d.src + (long long)bi * d.sstride;
    uint16_t* dst = d.dst + (long long)bi * d.dstride;
    int k0 = tk * 32, n0 = tn * 32;
#pragma unroll
    for (int p = 0; p < 4; p++) {
      int i = (tid >> 5) + p * 8;
      int k = k0 + i, n = n0 + (tid & 31);
      float v = 0.f;
      if (k < d.K && n < d.N) v = src[(long long)k * d.N + n];
      tile[i][tid & 31] = v;
    }
    __syncthreads();
#pragma unroll
    for (int p = 0; p < 4; p++) {
      int i = (tid >> 5) + p * 8;
      int n = n0 + i, k = k0 + (tid & 31);
      if (n < d.N && k < d.K) dst[(long long)n * d.K + k] = f2bf(tile[tid & 31][i]);
    }
    __syncthreads();
  }
}

// ---------------------------------------------------------------------------
// conv_w fp32 [384][2048][9] -> bf16 [384][9*2048] with K order (tap, ic)
// ---------------------------------------------------------------------------
__global__ __launch_bounds__(256) void conv_w_transpose(const float* __restrict__ src,
                                                        uint16_t* __restrict__ dst) {
  __shared__ float lds[2304];
  const int n = blockIdx.y;
  const int c0 = blockIdx.x * 256;
  const float* s = src + (size_t)n * 18432 + (size_t)c0 * 9;
  for (int j = threadIdx.x; j < 2304; j += 256) lds[j] = s[j];
  __syncthreads();
#pragma unroll
  for (int tap = 0; tap < 9; tap++)
    dst[(size_t)n * 18432 + tap * 2048 + c0 + threadIdx.x] =
        f2bf(lds[threadIdx.x * 9 + tap]);
}

// ---------------------------------------------------------------------------
// img_feat fp32 [32][2048][16][16] -> padded NHWC bf16 [32][18][18][2048]
// ---------------------------------------------------------------------------
__global__ __launch_bounds__(256) void img_pad_kernel(const float* __restrict__ img,
                                                      uint16_t* __restrict__ imgp) {
  __shared__ float tile[64][65];
  const int tid = threadIdx.x;
  const int b = blockIdx.z, ict = blockIdx.y, xyt = blockIdx.x;
  const int ic0 = ict * 64, xy0 = xyt * 64;
  const float* src = img + ((size_t)b * 2048 + ic0) * 256 + xy0;
#pragma unroll
  for (int p = 0; p < 16; p++) {
    int i = (tid >> 6) + p * 4;
    int j = tid & 63;
    tile[i][j] = src[(size_t)i * 256 + j];
  }
  __syncthreads();
#pragma unroll
  for (int p = 0; p < 16; p++) {
    int j = (tid >> 6) + p * 4;
    int i = tid & 63;
    int xy = xy0 + j;
    int y = xy >> 4, x = xy & 15;
    imgp[(((size_t)b * 18 + y + 1) * 18 + (x + 1)) * 2048 + ic0 + i] = f2bf(tile[i][j]);
  }
}

// ---------------------------------------------------------------------------
// prep: concat qkv biases to fp32 [8][2304]; convert vm/fm patches to bf16
// ---------------------------------------------------------------------------
__global__ __launch_bounds__(256) void prep_kernel(const float* __restrict__ bq,
                                                   const float* __restrict__ bk,
                                                   const float* __restrict__ bv,
                                                   float* __restrict__ bqkv,
                                                   const float* __restrict__ vm,
                                                   const float* __restrict__ fm,
                                                   uint16_t* __restrict__ vmb,
                                                   uint16_t* __restrict__ fmb) {
  int idx = blockIdx.x * 256 + threadIdx.x;
  if (idx < 2097152) {
    vmb[idx] = f2bf(vm[idx]);
    fmb[idx] = f2bf(fm[idx]);
  }
  if (idx < 18432) {
    int l = idx / 2304, c = idx % 2304;
    float v = (c < 768) ? bq[l * 768 + c]
                        : ((c < 1536) ? bk[l * 768 + c - 768] : bv[l * 768 + c - 1536]);
    bqkv[idx] = v;
  }
}

// ---------------------------------------------------------------------------
// x[:, 0:384] = convb[n] + pos[t][n]
// ---------------------------------------------------------------------------
__global__ __launch_bounds__(256) void xinit_kernel(const float* __restrict__ convb,
                                                    const float* __restrict__ pos,
                                                    float* __restrict__ x) {
  int idx = blockIdx.x * 256 + threadIdx.x;
  if (idx >= 8192 * 384) return;
  int m = idx / 384, n = idx % 384;
  x[(size_t)m * 768 + n] = convb[n] + pos[(size_t)(m & 255) * 768 + n];
}

// ---------------------------------------------------------------------------
// LayerNorm over 768: one wave per row, pure shfl reduction.
// ---------------------------------------------------------------------------
template <int BF16IN>
__global__ __launch_bounds__(256) void ln_kernel(const void* __restrict__ inv,
                                                 const float* __restrict__ g,
                                                 const float* __restrict__ bta,
                                                 uint16_t* __restrict__ out) {
  const int wave = threadIdx.x >> 6, lane = threadIdx.x & 63;
  const int row = blockIdx.x * 4 + wave;
  const float* inf = (const float*)inv;
  const uint16_t* inb = (const uint16_t*)inv;
  const size_t base = (size_t)row * 768;
  float v[12];
#pragma unroll
  for (int i = 0; i < 12; i++) {
    int c = lane + i * 64;
    v[i] = BF16IN ? bf2f(inb[base + c]) : inf[base + c];
  }
  float s = 0.f, s2 = 0.f;
#pragma unroll
  for (int i = 0; i < 12; i++) {
    s += v[i];
    s2 += v[i] * v[i];
  }
#pragma unroll
  for (int d = 1; d < 64; d <<= 1) {
    s += __shfl_xor(s, d, 64);
    s2 += __shfl_xor(s2, d, 64);
  }
  float mean = s * (1.f / 768.f);
  float var = s2 * (1.f / 768.f) - mean * mean;
  float rs = rsqrtf(var + 1e-5f);
#pragma unroll
  for (int i = 0; i < 12; i++) {
    int c = lane + i * 64;
    out[base + c] = f2bf((v[i] - mean) * rs * g[c] + bta[c]);
  }
}

// ---------------------------------------------------------------------------
// Small-N GEMM (vm/fm embeds, N=192): 128x64 tile, serial K-loop.
// ---------------------------------------------------------------------------
template <int AMODE, int EPI>
__global__ __launch_bounds__(256, 4) void gemm_kernel(
    const uint16_t* __restrict__ A, const uint16_t* __restrict__ Bt,
    const float* __restrict__ bias, int N, int K,
    float* xout,
    const float* __restrict__ pos, int colOff,
    uint16_t* __restrict__ outb, float* __restrict__ outf, int ldc) {
  __shared__ uint16_t ldsA[8192];
  __shared__ uint16_t ldsB[4096];
  const int tid = threadIdx.x;
  const int lane = tid & 63, wave = tid >> 6;
  const int l15 = lane & 15, q8 = (lane >> 4) << 3;
  const int row0 = blockIdx.x * 128, col0 = blockIdx.y * 64;
  const int kPer = K / (int)gridDim.z;
  const int kbeg = kPer * (int)blockIdx.z;
  const int wm = wave & 1, wn = wave >> 1;

  const uint16_t* srcP[6];
  uint16_t* dstP[6];
#pragma unroll
  for (int c = 0; c < 6; c++) {
    int j = wave * 6 + c;
    if (j < 16) {
      int mt8 = j >> 1, ks = j & 1;
      int m = row0 + mt8 * 16 + l15;
      srcP[c] = A + (size_t)m * K + ks * 32 + q8;
      dstP[c] = &ldsA[j * 512];
    } else {
      int fb = j - 16;
      int nt = fb >> 1, ks = fb & 1;
      int n = col0 + nt * 16 + l15;
      srcP[c] = Bt + (size_t)n * K + ks * 32 + q8;
      dstP[c] = &ldsB[fb * 512];
    }
  }

  v4f acc[4][2];
#pragma unroll
  for (int i = 0; i < 4; i++)
#pragma unroll
    for (int j = 0; j < 2; j++) acc[i][j] = (v4f){0.f, 0.f, 0.f, 0.f};

  for (int k0 = kbeg; k0 < kbeg + kPer; k0 += 64) {
    __syncthreads();
#pragma unroll
    for (int c = 0; c < 6; c++) gld16(srcP[c] + (size_t)k0, dstP[c]);
    __syncthreads();
#pragma unroll
    for (int ks = 0; ks < 2; ks++) {
      short8 af[4], bfr[2];
#pragma unroll
      for (int mt = 0; mt < 4; mt++)
        af[mt] = *(const short8*)&ldsA[(((wm * 4 + mt) * 2) + ks) * 512 + lane * 8];
#pragma unroll
      for (int nt = 0; nt < 2; nt++)
        bfr[nt] = *(const short8*)&ldsB[(((wn * 2 + nt) * 2) + ks) * 512 + lane * 8];
#pragma unroll
      for (int mt = 0; mt < 4; mt++)
#pragma unroll
        for (int nt = 0; nt < 2; nt++)
          acc[mt][nt] =
              __builtin_amdgcn_mfma_f32_16x16x32_bf16(af[mt], bfr[nt], acc[mt][nt], 0, 0, 0);
    }
  }

#pragma unroll
  for (int mt = 0; mt < 4; mt++) {
    int mbase = row0 + wm * 64 + mt * 16 + ((lane >> 4) << 2);
#pragma unroll
    for (int nt = 0; nt < 2; nt++) {
      int n = col0 + wn * 32 + nt * 16 + l15;
      float bv;
      if (EPI == EPI_ATOM)
        bv = (bias != nullptr && blockIdx.z == 0) ? bias[n] : 0.f;
      else if (EPI == EPI_ATOMOUT)
        bv = (blockIdx.z == 0) ? bias[n] : 0.f;
      else
        bv = bias[n];
      v4f a = acc[mt][nt];
#pragma unroll
      for (int r = 0; r < 4; r++) {
        int m = mbase + r;
        float v = a[r] + bv;
        if (EPI == EPI_BF16) {
          outb[(size_t)m * ldc + n] = f2bf(v);
        } else if (EPI == EPI_GELU) {
          outb[(size_t)m * ldc + n] = f2bf(gelu_f(v));
        } else if (EPI == EPI_XPOS) {
          xout[(size_t)m * 768 + colOff + n] = v + pos[(size_t)(m & 255) * 768 + colOff + n];
        } else if (EPI == EPI_ATOM) {
          atomicAdd(&xout[(size_t)m * 768 + colOff + n], v);
        } else if (EPI == EPI_ATOMOUT) {
          atomicAdd(&outf[(size_t)m * ldc + n], v);
        }
      }
    }
  }
}

// ---------------------------------------------------------------------------
// Mid GEMM (dec/head): 128x128 tile, dbuf + counted vmcnt.
// ---------------------------------------------------------------------------
template <int EPI>
__global__ __launch_bounds__(256, 2) void gemm128_kernel(
    const uint16_t* __restrict__ A, const uint16_t* __restrict__ Bt,
    const float* __restrict__ bias, int N, int K,
    float* xout,
    uint16_t* __restrict__ outb, float* __restrict__ outf, int ldc) {
  __shared__ uint16_t lds[2][16384];
  const int tid = threadIdx.x;
  const int lane = tid & 63, wave = tid >> 6;
  const int l15 = lane & 15, q8 = (lane >> 4) << 3;
  const int row0 = blockIdx.x * 128, col0 = blockIdx.y * 128;
  const int kPer = K / (int)gridDim.z;
  const int kbeg = kPer * (int)blockIdx.z;
  const int nt = kPer >> 6;
  const int wm = wave & 1, wn = wave >> 1;

  const uint16_t* srcP[8];
  int off[8];
#pragma unroll
  for (int c = 0; c < 8; c++) {
    int j = wave * 8 + c;
    if (j < 16) {
      int mt8 = j >> 1, ks = j & 1;
      int m = row0 + mt8 * 16 + l15;
      srcP[c] = A + (size_t)m * K + kbeg + ks * 32 + q8;
      off[c] = j * 512;
    } else {
      int fb = j - 16;
      int nt16 = fb >> 1, ks = fb & 1;
      int n = col0 + nt16 * 16 + l15;
      srcP[c] = Bt + (size_t)n * K + kbeg + ks * 32 + q8;
      off[c] = 8192 + fb * 512;
    }
  }

  auto STAGE = [&](int t) {
    size_t ko = (size_t)(t * 64);
    uint16_t* lb = &lds[t & 1][0];
#pragma unroll
    for (int c = 0; c < 8; c++) gld16(srcP[c] + ko, lb + off[c]);
  };

  v4f acc[4][4];
#pragma unroll
  for (int i = 0; i < 4; i++)
#pragma unroll
    for (int j = 0; j < 4; j++) acc[i][j] = (v4f){0.f, 0.f, 0.f, 0.f};

  STAGE(0);
  if (nt > 1) STAGE(1);

  for (int t = 0; t < nt; t++) {
    if (t + 1 < nt)
      asm volatile("s_waitcnt vmcnt(8)" ::: "memory");
    else
      asm volatile("s_waitcnt vmcnt(0)" ::: "memory");
    __builtin_amdgcn_s_barrier();

    const uint16_t* lb = &lds[t & 1][0];
#pragma unroll
    for (int ks = 0; ks < 2; ks++) {
      short8 af[4], bfr[4];
#pragma unroll
      for (int mt = 0; mt < 4; mt++)
        af[mt] = *(const short8*)&lb[(((wm * 4 + mt) * 2) + ks) * 512 + lane * 8];
#pragma unroll
      for (int nt2 = 0; nt2 < 4; nt2++)
        bfr[nt2] = *(const short8*)&lb[8192 + (((wn * 4 + nt2) * 2) + ks) * 512 + lane * 8];
#pragma unroll
      for (int mt = 0; mt < 4; mt++)
#pragma unroll
        for (int nt2 = 0; nt2 < 4; nt2++)
          acc[mt][nt2] =
              __builtin_amdgcn_mfma_f32_16x16x32_bf16(af[mt], bfr[nt2], acc[mt][nt2], 0, 0, 0);
    }

    __builtin_amdgcn_s_barrier();
    if (t + 2 < nt) STAGE(t + 2);
  }

#pragma unroll
  for (int mt = 0; mt < 4; mt++) {
    int mbase = row0 + wm * 64 + mt * 16 + ((lane >> 4) << 2);
#pragma unroll
    for (int nt2 = 0; nt2 < 4; nt2++) {
      int n = col0 + wn * 64 + nt2 * 16 + l15;
      float bv;
      if (EPI == EPI_ATOMOUT)
        bv = (blockIdx.z == 0) ? bias[n] : 0.f;
      else
        bv = bias[n];
      v4f a = acc[mt][nt2];
#pragma unroll
      for (int r = 0; r < 4; r++) {
        int m = mbase + r;
        float v = a[r] + bv;
        if (EPI == EPI_BF16) {
          outb[(size_t)m * ldc + n] = f2bf(v);
        } else if (EPI == EPI_GELU) {
          outb[(size_t)m * ldc + n] = f2bf(gelu_f(v));
        } else if (EPI == EPI_ATOMOUT) {
          atomicAdd(&outf[(size_t)m * ldc + n], v);
        }
      }
    }
  }
}

// ---------------------------------------------------------------------------
// Main GEMM: 256x256 tile, 8-wave 4-phase schedule with read-ahead (verified
// r4/r5 sync skeleton; 512 threads = residency-feasible register budget).
// ---------------------------------------------------------------------------
template <int AMODE, int EPI>
__global__ __launch_bounds__(512, 2) void gemm256_kernel(
    const uint16_t* __restrict__ A, const uint16_t* __restrict__ Bt,
    const float* __restrict__ bias, int N, int K,
    float* xout, uint16_t* __restrict__ outb, float* __restrict__ outf, int ldc) {
  extern __shared__ uint16_t lds[];  // [2][32768]: per buf A 16384 | B 16384
  const int tid = threadIdx.x;
  const int lane = tid & 63, wave = tid >> 6;
  const int l15 = lane & 15, q8 = (lane >> 4) << 3;
  const int row0 = blockIdx.x * 256, col0 = blockIdx.y * 256;
  const int kPer = K / (int)gridDim.z;
  const int kbeg = kPer * (int)blockIdx.z;
  const int nt = kPer >> 6;
  const int wm = wave >> 2, wn = wave & 3;

  const uint16_t* src[4][2];
  int ldsoff[4][2];
#pragma unroll
  for (int c = 0; c < 2; c++) {
    int sub = wave * 2 + c;  // [0,16)
    int hf = sub >> 1, ks = sub & 1;
    int kin = ks * 32 + q8;
    int m0 = row0 + hf * 16 + l15;
    int m1 = m0 + 128;
    if (AMODE == 0) {
      src[0][c] = A + (size_t)m0 * K + kin;
      src[3][c] = A + (size_t)m1 * K + kin;
    } else {
      int b0_ = m0 >> 8, y0_ = (m0 >> 4) & 15, x0_ = m0 & 15;
      src[0][c] = A + ((size_t)((b0_ * 18 + y0_) * 18 + x0_)) * 2048 + kin;
      int b1_ = m1 >> 8, y1_ = (m1 >> 4) & 15, x1_ = m1 & 15;
      src[3][c] = A + ((size_t)((b1_ * 18 + y1_) * 18 + x1_)) * 2048 + kin;
    }
    src[1][c] = Bt + (size_t)(col0 + hf * 16 + l15) * K + kin;
    src[2][c] = Bt + (size_t)(col0 + 128 + hf * 16 + l15) * K + kin;
    ldsoff[0][c] = sub * 512;
    ldsoff[3][c] = (16 + sub) * 512;
    ldsoff[1][c] = 16384 + sub * 512;
    ldsoff[2][c] = 16384 + (16 + sub) * 512;
  }

#define STAGEH(TT, Q)                                                          \
  do {                                                                         \
    int t_ = (TT);                                                             \
    if (t_ < nt) {                                                             \
      int k0_ = kbeg + t_ * 64;                                                \
      size_t o_;                                                               \
      if (AMODE == 1 && ((Q) == 0 || (Q) == 3)) {                              \
        int kq_ = k0_ >> 11;                                                   \
        int ky_ = (kq_ >= 6) ? 2 : ((kq_ >= 3) ? 1 : 0);                       \
        int kx_ = kq_ - ky_ * 3;                                               \
        o_ = (size_t)((ky_ * 18 + kx_) * 2048) + (size_t)(k0_ & 2047);         \
      } else {                                                                 \
        o_ = (size_t)k0_;                                                      \
      }                                                                        \
      uint16_t* lb_ = &lds[(t_ & 1) * 32768];                                  \
      gld16(src[Q][0] + o_, lb_ + ldsoff[Q][0]);                               \
      gld16(src[Q][1] + o_, lb_ + ldsoff[Q][1]);                               \
    }                                                                          \
  } while (0)

  v4f acc[8][4];
#pragma unroll
  for (int i = 0; i < 8; i++)
#pragma unroll
    for (int j = 0; j < 4; j++) acc[i][j] = (v4f){0.f, 0.f, 0.f, 0.f};

  STAGEH(0, 0); STAGEH(0, 1); STAGEH(0, 2); STAGEH(0, 3);
  STAGEH(1, 1); STAGEH(1, 0);
  asm volatile("s_waitcnt vmcnt(4)" ::: "memory");
  __builtin_amdgcn_s_barrier();

  short8 a_[4][2], aN[4][2], b0_[2][2], b1_[2][2];

#pragma unroll
  for (int mt = 0; mt < 4; mt++)
#pragma unroll
    for (int ks = 0; ks < 2; ks++)
      aN[mt][ks] = *(const short8*)&lds[((wm * 8 + mt) * 2 + ks) * 512 + lane * 8];

  for (int t = 0; t < nt; t++) {
    const int bufo = (t & 1) * 32768;

#pragma unroll
    for (int nl = 0; nl < 2; nl++)
#pragma unroll
      for (int ks = 0; ks < 2; ks++)
        b0_[nl][ks] =
            *(const short8*)&lds[bufo + 16384 + ((wn * 4 + nl) * 2 + ks) * 512 + lane * 8];
#pragma unroll
    for (int nl = 0; nl < 2; nl++)
#pragma unroll
      for (int ks = 0; ks < 2; ks++)
        b1_[nl][ks] =
            *(const short8*)&lds[bufo + 16384 + ((wn * 4 + 2 + nl) * 2 + ks) * 512 + lane * 8];
    STAGEH(t + 1, 2);
    __builtin_amdgcn_s_barrier();
    __builtin_amdgcn_s_setprio(1);
#pragma unroll
    for (int mt = 0; mt < 4; mt++)
#pragma unroll
      for (int nl = 0; nl < 2; nl++)
#pragma unroll
        for (int ks = 0; ks < 2; ks++)
          acc[mt][nl] =
              __builtin_amdgcn_mfma_f32_16x16x32_bf16(aN[mt][ks], b0_[nl][ks], acc[mt][nl], 0, 0, 0);
    __builtin_amdgcn_s_setprio(0);
    __builtin_amdgcn_s_barrier();

#pragma unroll
    for (int mt = 0; mt < 4; mt++)
#pragma unroll
      for (int ks = 0; ks < 2; ks++)
        a_[mt][ks] =
            *(const short8*)&lds[bufo + ((wm * 8 + 4 + mt) * 2 + ks) * 512 + lane * 8];
    STAGEH(t + 1, 3);
    __builtin_amdgcn_s_barrier();
    __builtin_amdgcn_s_setprio(1);
#pragma unroll
    for (int mt = 0; mt < 4; mt++)
#pragma unroll
      for (int nl = 0; nl < 2; nl++)
#pragma unroll
        for (int ks = 0; ks < 2; ks++)
          acc[mt][2 + nl] =
              __builtin_amdgcn_mfma_f32_16x16x32_bf16(aN[mt][ks], b1_[nl][ks], acc[mt][2 + nl], 0, 0, 0);
    __builtin_amdgcn_s_setprio(0);
    __builtin_amdgcn_s_barrier();

    STAGEH(t + 2, 1);
    __builtin_amdgcn_s_barrier();
    __builtin_amdgcn_s_setprio(1);
#pragma unroll
    for (int mt = 0; mt < 4; mt++)
#pragma unroll
      for (int nl = 0; nl < 2; nl++)
#pragma unroll
        for (int ks = 0; ks < 2; ks++)
          acc[4 + mt][2 + nl] =
              __builtin_amdgcn_mfma_f32_16x16x32_bf16(a_[mt][ks], b1_[nl][ks], acc[4 + mt][2 + nl], 0, 0, 0);
    __builtin_amdgcn_s_setprio(0);
    __builtin_amdgcn_s_barrier();

    STAGEH(t + 2, 0);
    if (t < nt - 1) {
      if (t == nt - 2)
        asm volatile("s_waitcnt vmcnt(0)" ::: "memory");
      else
        asm volatile("s_waitcnt vmcnt(4)" ::: "memory");
    }
    __builtin_amdgcn_s_barrier();
    if (t + 1 < nt) {
      const int bufn = ((t + 1) & 1) * 32768;
#pragma unroll
      for (int mt = 0; mt < 4; mt++)
#pragma unroll
        for (int ks = 0; ks < 2; ks++)
          aN[mt][ks] =
              *(const short8*)&lds[bufn + ((wm * 8 + mt) * 2 + ks) * 512 + lane * 8];
    }
    __builtin_amdgcn_s_setprio(1);
#pragma unroll
    for (int mt = 0; mt < 4; mt++)
#pragma unroll
      for (int nl = 0; nl < 2; nl++)
#pragma unroll
        for (int ks = 0; ks < 2; ks++)
          acc[4 + mt][nl] =
              __builtin_amdgcn_mfma_f32_16x16x32_bf16(a_[mt][ks], b0_[nl][ks], acc[4 + mt][nl], 0, 0, 0);
    __builtin_amdgcn_s_setprio(0);
    __builtin_amdgcn_s_barrier();
  }
#undef STAGEH

#pragma unroll
  for (int mt = 0; mt < 8; mt++) {
    int mbase = row0 + wm * 128 + mt * 16 + ((lane >> 4) << 2);
#pragma unroll
    for (int nl = 0; nl < 4; nl++) {
      int n = col0 + wn * 64 + nl * 16 + l15;
      float bv;
      if (EPI == EPI_ATOM)
        bv = (bias != nullptr && blockIdx.z == 0) ? bias[n] : 0.f;
      else
        bv = bias[n];
      v4f a = acc[mt][nl];
#pragma unroll
      for (int r = 0; r < 4; r++) {
        int m = mbase + r;
        float v = a[r] + bv;
        if (EPI == EPI_BF16) {
          outb[(size_t)m * ldc + n] = f2bf(v);
        } else if (EPI == EPI_GELU) {
          outb[(size_t)m * ldc + n] = f2bf(gelu_f(v));
        } else if (EPI == EPI_ATOM) {
          atomicAdd(&xout[(size_t)m * 768 + n], v);
        }
      }
    }
  }
}

// ---------------------------------------------------------------------------
// Fused attention (r7-verified body: 256 thr, 4 waves, 64 q-rows/block,
// P aliases K, Vt col-swizzled; 2 blocks/CU, 1536 blocks = 3 exact rounds).
// NEW: XCD-sibling grid permutation. 1-D grid, lin = blockIdx.x:
//   hb = (lin>>5)*8 + (lin&7),  qc = (lin>>3)&3,  h = hb%12, b = hb/12
// Bijective on [0,1536). The 4 qc-siblings of an (h,b) have linear ids
// differing by 8 -> same XCD (round-robin dispatch) -> they share one L2
// copy of K/V (64 KB) instead of fetching it through 4 different XCD L2s.
// (r8's per-(h,b)-block variant removed this redundancy but broke makespan:
// 384 blocks @1/CU = 2 rounds x 2x block time vs 3 balanced rounds here.)
// ---------------------------------------------------------------------------
__global__ __launch_bounds__(256) void attn_kernel(const uint16_t* __restrict__ qkv,
                                                   uint16_t* __restrict__ y) {
  __shared__ uint16_t KP[18432];      // aliases Kl[256*72] and Pl[4][16*264]
  __shared__ uint16_t Vt[64 * 264];   // V^T rows, stride 264, col-swizzled
  uint16_t* Kl = KP;
  uint16_t(*Pl)[16 * 264] = (uint16_t(*)[16 * 264])KP;
  const int tid = threadIdx.x, lane = tid & 63, wave = tid >> 6;
  const int lin = blockIdx.x;
  const int hb = ((lin >> 5) << 3) | (lin & 7);
  const int qc = (lin >> 3) & 3;
  const int h = hb % 12, b = hb / 12;
  const uint16_t* base = qkv + (size_t)b * 256 * 2304;
  const uint16_t* kb = base + 768 + h * 64;
  const uint16_t* vb = base + 1536 + h * 64;

#pragma unroll
  for (int i = 0; i < 8; i++) {
    int c = i * 256 + tid;
    int t = c >> 3, dh = (c & 7) * 8;
    uint4 d = *(const uint4*)(kb + (size_t)t * 2304 + dh);
    *(uint4*)&Kl[t * 72 + dh] = d;
  }
#pragma unroll
  for (int i = 0; i < 8; i++) {
    int c = i * 256 + tid;
    int t = c >> 3, dh = (c & 7) * 8;
    uint4 d = *(const uint4*)(vb + (size_t)t * 2304 + dh);
    const uint16_t* e = (const uint16_t*)&d;
    int tc = t ^ (((dh >> 3) & 7) << 3);  // col swizzle (row>>3 == dh>>3)
#pragma unroll
    for (int j = 0; j < 8; j++) Vt[(dh + j) * 264 + tc] = e[j];
  }
  __syncthreads();

  const int t0 = qc * 64 + wave * 16;
  const uint16_t* qb = base + h * 64;
  const int l15 = lane & 15, q4 = (lane >> 4) << 3;
  short8 aq0 = *(const short8*)(qb + (size_t)(t0 + l15) * 2304 + q4);
  short8 aq1 = *(const short8*)(qb + (size_t)(t0 + l15) * 2304 + 32 + q4);

  v4f s[16];
#pragma unroll
  for (int jt = 0; jt < 16; jt++) {
    short8 b0 = *(const short8*)&Kl[(jt * 16 + l15) * 72 + q4];
    short8 b1 = *(const short8*)&Kl[(jt * 16 + l15) * 72 + 32 + q4];
    v4f z = (v4f){0.f, 0.f, 0.f, 0.f};
    z = __builtin_amdgcn_mfma_f32_16x16x32_bf16(aq0, b0, z, 0, 0, 0);
    s[jt] = __builtin_amdgcn_mfma_f32_16x16x32_bf16(aq1, b1, z, 0, 0, 0);
  }

  float mx[4], sm[4];
#pragma unroll
  for (int r = 0; r < 4; r++) mx[r] = -1e30f;
#pragma unroll
  for (int jt = 0; jt < 16; jt++)
#pragma unroll
    for (int r = 0; r < 4; r++) {
      float v = s[jt][r] * 0.125f;
      s[jt][r] = v;
      mx[r] = fmaxf(mx[r], v);
    }
#pragma unroll
  for (int r = 0; r < 4; r++) {
#pragma unroll
    for (int d = 1; d < 16; d <<= 1) mx[r] = fmaxf(mx[r], __shfl_xor(mx[r], d, 64));
    sm[r] = 0.f;
  }
#pragma unroll
  for (int jt = 0; jt < 16; jt++)
#pragma unroll
    for (int r = 0; r < 4; r++) {
      float e = __expf(s[jt][r] - mx[r]);
      s[jt][r] = e;
      sm[r] += e;
    }
#pragma unroll
  for (int r = 0; r < 4; r++) {
#pragma unroll
    for (int d = 1; d < 16; d <<= 1) sm[r] += __shfl_xor(sm[r], d, 64);
    sm[r] = 1.f / sm[r];
  }

  __syncthreads();  // all waves done reading Kl before P overwrites it

  const int rbase = (lane >> 4) << 2;
#pragma unroll
  for (int jt = 0; jt < 16; jt++)
#pragma unroll
    for (int r = 0; r < 4; r++)
      Pl[wave][(rbase + r) * 264 + jt * 16 + l15] = f2bf(s[jt][r] * sm[r]);
  __syncthreads();

  v4f o[4];
#pragma unroll
  for (int nt = 0; nt < 4; nt++) o[nt] = (v4f){0.f, 0.f, 0.f, 0.f};
#pragma unroll
  for (int ks = 0; ks < 8; ks++) {
    short8 ap = *(const short8*)&Pl[wave][l15 * 264 + ks * 32 + q4];
#pragma unroll
    for (int nt = 0; nt < 4; nt++) {
      int row = nt * 16 + l15;
      int col = (ks * 32 + q4) ^ (((row >> 3) & 7) << 3);
      short8 bv8 = *(const short8*)&Vt[row * 264 + col];
      o[nt] = __builtin_amdgcn_mfma_f32_16x16x32_bf16(ap, bv8, o[nt], 0, 0, 0);
    }
  }
#pragma unroll
  for (int nt = 0; nt < 4; nt++)
#pragma unroll
    for (int r = 0; r < 4; r++)
      y[(size_t)(b * 256 + t0 + rbase + r) * 768 + h * 64 + nt * 16 + l15] = f2bf(o[nt][r]);
}

// ---------------------------------------------------------------------------
// host
// ---------------------------------------------------------------------------
extern "C" void kernel_launch(void* const* d_in, const int* in_sizes, int n_in,
                              void* d_out, int out_size, void* d_ws, size_t ws_size,
                              hipStream_t stream) {
  const float* img   = (const float*)d_in[0];
  const float* vmp   = (const float*)d_in[1];
  const float* fmp   = (const float*)d_in[2];
  const float* convw = (const float*)d_in[3];
  const float* convb = (const float*)d_in[4];
  const float* vmw   = (const float*)d_in[5];
  const float* vmb_  = (const float*)d_in[6];
  const float* fmw   = (const float*)d_in[7];
  const float* fmb_  = (const float*)d_in[8];
  const float* pos   = (const float*)d_in[9];
  const float* ln1g  = (const float*)d_in[10];
  const float* ln1b  = (const float*)d_in[11];
  const float* Wq    = (const float*)d_in[12];
  const float* bq    = (const float*)d_in[13];
  const float* Wk    = (const float*)d_in[14];
  const float* bk    = (const float*)d_in[15];
  const float* Wv    = (const float*)d_in[16];
  const float* bv    = (const float*)d_in[17];
  const float* Wo    = (const float*)d_in[18];
  const float* bo    = (const float*)d_in[19];
  const float* ln2g  = (const float*)d_in[20];
  const float* ln2b  = (const float*)d_in[21];
  const float* W1    = (const float*)d_in[22];
  const float* b1    = (const float*)d_in[23];
  const float* W2    = (const float*)d_in[24];
  const float* b2    = (const float*)d_in[25];
  const float* dln1g = (const float*)d_in[26];
  const float* dln1b = (const float*)d_in[27];
  const float* decw  = (const float*)d_in[28];
  const float* decb  = (const float*)d_in[29];
  const float* dln2g = (const float*)d_in[30];
  const float* dln2b = (const float*)d_in[31];
  const float* headw = (const float*)d_in[32];
  const float* headb = (const float*)d_in[33];
  float* out = (float*)d_out;

  char* wsb = (char*)d_ws;
  size_t off = 0;
  auto alloc = [&](size_t nbytes) -> void* {
    off = (off + 255) & ~(size_t)255;
    void* p = wsb + off;
    off += nbytes;
    return p;
  };
  uint16_t* WtQKV  = (uint16_t*)alloc(8ull * 2304 * 768 * 2);
  uint16_t* WtO    = (uint16_t*)alloc(8ull * 768 * 768 * 2);
  uint16_t* Wt1    = (uint16_t*)alloc(8ull * 3072 * 768 * 2);
  uint16_t* Wt2    = (uint16_t*)alloc(8ull * 768 * 3072 * 2);
  uint16_t* WtConv = (uint16_t*)alloc(512ull * 9 * 2048 * 2);  // padded to 512 rows
  uint16_t* WtVm   = (uint16_t*)alloc(192ull * 256 * 2);
  uint16_t* WtFm   = (uint16_t*)alloc(192ull * 256 * 2);
  uint16_t* WtDec  = (uint16_t*)alloc(768ull * 768 * 2);
  uint16_t* WtHead = (uint16_t*)alloc(256ull * 768 * 2);
  uint16_t* imgp   = (uint16_t*)alloc(32ull * 18 * 18 * 2048 * 2);
  uint16_t* vmb    = (uint16_t*)alloc(8192ull * 256 * 2);
  uint16_t* fmb    = (uint16_t*)alloc(8192ull * 256 * 2);
  float*    bqkv   = (float*)alloc(8ull * 2304 * 4);
  float*    x      = (float*)alloc(8192ull * 768 * 4);
  uint16_t* hbuf   = (uint16_t*)alloc(8192ull * 768 * 2);
  uint16_t* qkvb   = (uint16_t*)alloc(8192ull * 2304 * 2);
  uint16_t* ybuf   = (uint16_t*)alloc(8192ull * 768 * 2);
  uint16_t* ubuf   = (uint16_t*)alloc(8192ull * 3072 * 2);
  uint16_t* u2buf  = (uint16_t*)alloc(8192ull * 768 * 2);
  if (off > ws_size) return;

  hipMemsetAsync(imgp, 0, 32ull * 18 * 18 * 2048 * 2, stream);
  hipMemsetAsync(WtConv, 0, 512ull * 9 * 2048 * 2, stream);
  hipMemsetAsync(out, 0, (size_t)out_size * 4, stream);

  hipFuncSetAttribute((const void*)gemm256_kernel<1, EPI_ATOM>,
                      hipFuncAttributeMaxDynamicSharedMemorySize, 131072);
  hipFuncSetAttribute((const void*)gemm256_kernel<0, EPI_ATOM>,
                      hipFuncAttributeMaxDynamicSharedMemorySize, 131072);
  hipFuncSetAttribute((const void*)gemm256_kernel<0, EPI_BF16>,
                      hipFuncAttributeMaxDynamicSharedMemorySize, 131072);
  hipFuncSetAttribute((const void*)gemm256_kernel<0, EPI_GELU>,
                      hipFuncAttributeMaxDynamicSharedMemorySize, 131072);

  TTable tt;
  int nd = 0;
  long long tiles = 0;
  auto addT = [&](const float* src, uint16_t* dst, int K, int N, int batch,
                  long long sstr, long long dstr) {
    TDesc& d = tt.d[nd];
    d.src = src; d.dst = dst; d.K = K; d.N = N; d.batch = batch;
    d.sstride = sstr; d.dstride = dstr;
    d.tilesK = (K + 31) / 32; d.tilesN = (N + 31) / 32;
    d.tileStart = tiles;
    tiles += (long long)d.tilesK * d.tilesN * batch;
    nd++;
  };
  addT(Wq, WtQKV,           768, 768, 8, 589824, 1769472);
  addT(Wk, WtQKV + 589824,  768, 768, 8, 589824, 1769472);
  addT(Wv, WtQKV + 1179648, 768, 768, 8, 589824, 1769472);
  addT(Wo, WtO,             768, 768, 8, 589824, 589824);
  addT(W1, Wt1,             768, 3072, 8, 2359296, 2359296);
  addT(W2, Wt2,             3072, 768, 8, 2359296, 2359296);
  addT(vmw, WtVm,           256, 192, 1, 0, 0);
  addT(fmw, WtFm,           256, 192, 1, 0, 0);
  addT(decw, WtDec,         768, 768, 1, 0, 0);
  addT(headw, WtHead,       768, 256, 1, 0, 0);
  tt.nd = nd;
  tt.totalTiles = tiles;

  transpose_convert_kernel<<<(int)tiles, 256, 0, stream>>>(tt);
  conv_w_transpose<<<dim3(8, 384), 256, 0, stream>>>(convw, WtConv);
  img_pad_kernel<<<dim3(4, 32, 32), 256, 0, stream>>>(img, imgp);
  prep_kernel<<<8192, 256, 0, stream>>>(bq, bk, bv, bqkv, vmp, fmp, vmb, fmb);
  xinit_kernel<<<12288, 256, 0, stream>>>(convb, pos, x);

  // conv token embed: N padded 384->512, grid exactly 256 blocks.
  gemm256_kernel<1, EPI_ATOM><<<dim3(32, 2, 4), 512, 131072, stream>>>(
      imgp, WtConv, nullptr, 512, 18432, x, nullptr, nullptr, 0);
  gemm_kernel<0, EPI_XPOS><<<dim3(64, 3), 256, 0, stream>>>(
      vmb, WtVm, vmb_, 192, 256, x, pos, 384, nullptr, nullptr, 0);
  gemm_kernel<0, EPI_XPOS><<<dim3(64, 3), 256, 0, stream>>>(
      fmb, WtFm, fmb_, 192, 256, x, pos, 576, nullptr, nullptr, 0);

  for (int l = 0; l < 8; l++) {
    ln_kernel<0><<<2048, 256, 0, stream>>>(x, ln1g + l * 768, ln1b + l * 768, hbuf);
    gemm256_kernel<0, EPI_BF16><<<dim3(32, 9), 512, 131072, stream>>>(
        hbuf, WtQKV + (size_t)l * 1769472, bqkv + l * 2304, 2304, 768,
        nullptr, qkvb, nullptr, 2304);
    attn_kernel<<<1536, 256, 0, stream>>>(qkvb, ybuf);
    gemm256_kernel<0, EPI_ATOM><<<dim3(32, 3, 2), 512, 131072, stream>>>(
        ybuf, WtO + (size_t)l * 589824, bo + l * 768, 768, 768,
        x, nullptr, nullptr, 0);
    ln_kernel<0><<<2048, 256, 0, stream>>>(x, ln2g + l * 768, ln2b + l * 768, hbuf);
    gemm256_kernel<0, EPI_GELU><<<dim3(32, 12), 512, 131072, stream>>>(
        hbuf, Wt1 + (size_t)l * 2359296, b1 + l * 3072, 3072, 768,
        nullptr, ubuf, nullptr, 3072);
    gemm256_kernel<0, EPI_ATOM><<<dim3(32, 3, 2), 512, 131072, stream>>>(
        ubuf, Wt2 + (size_t)l * 2359296, b2 + l * 768, 768, 3072,
        x, nullptr, nullptr, 0);
  }

  ln_kernel<0><<<2048, 256, 0, stream>>>(x, dln1g, dln1b, hbuf);
  gemm128_kernel<EPI_GELU><<<dim3(64, 6), 256, 0, stream>>>(
      hbuf, WtDec, decb, 768, 768, nullptr, u2buf, nullptr, 768);
  ln_kernel<1><<<2048, 256, 0, stream>>>(u2buf, dln2g, dln2b, hbuf);
  gemm128_kernel<EPI_ATOMOUT><<<dim3(64, 2, 2), 256, 0, stream>>>(
      hbuf, WtHead, headb, 256, 768, nullptr, nullptr, out, 256);
}